// Round 1
// baseline (6251.694 us; speedup 1.0000x reference)
//
#include <hip/hip_runtime.h>

#define N_USERS 100000
#define N_ITEMS 50000
#define N_NODES (N_USERS + N_ITEMS)   // 150000
#define DIM 64
#define NNZ_TOTAL 10000000
#define TOTAL (N_NODES * DIM)         // 9,600,000 floats
#define TOTAL4 (TOTAL / 4)            // 2,400,000 float4
#define USZ4 (N_USERS * DIM / 4)      // 1,600,000 float4

// ---------------------------------------------------------------------------
// init: A = concat(user, item); acc(d_out) = same
// ---------------------------------------------------------------------------
__global__ __launch_bounds__(256) void k_init(const float4* __restrict__ user,
                                              const float4* __restrict__ item,
                                              float4* __restrict__ A,
                                              float4* __restrict__ acc) {
    const int stride = gridDim.x * blockDim.x;
    for (int i = blockIdx.x * blockDim.x + threadIdx.x; i < TOTAL4; i += stride) {
        float4 v = (i < USZ4) ? user[i] : item[i - USZ4];
        A[i] = v;
        acc[i] = v;
    }
}

// ---------------------------------------------------------------------------
// SpMM scatter: one edge per wave; lane d owns dim element d.
// B[r*64+d] += val * A[c*64+d]   (B pre-zeroed)
// ---------------------------------------------------------------------------
__global__ __launch_bounds__(256) void k_spmm(const float* __restrict__ A,
                                              float* __restrict__ B,
                                              const float* __restrict__ val,
                                              const int* __restrict__ row,
                                              const int* __restrict__ col) {
    const int lane = threadIdx.x & 63;
    int wave = blockIdx.x * (blockDim.x >> 6) + (threadIdx.x >> 6);
    const int nw = gridDim.x * (blockDim.x >> 6);
    for (int e = wave; e < NNZ_TOTAL; e += nw) {
        const int r = row[e];
        const int c = col[e];
        const float v = val[e];
        const float x = A[c * DIM + lane];
        unsafeAtomicAdd(&B[r * DIM + lane], v * x);
    }
}

// ---------------------------------------------------------------------------
// acc += B
// ---------------------------------------------------------------------------
__global__ __launch_bounds__(256) void k_accadd(float4* __restrict__ acc,
                                                const float4* __restrict__ B) {
    const int stride = gridDim.x * blockDim.x;
    for (int i = blockIdx.x * blockDim.x + threadIdx.x; i < TOTAL4; i += stride) {
        float4 a = acc[i];
        const float4 b = B[i];
        a.x += b.x; a.y += b.y; a.z += b.z; a.w += b.w;
        acc[i] = a;
    }
}

// ---------------------------------------------------------------------------
// acc = (acc + B) * 0.25
// ---------------------------------------------------------------------------
__global__ __launch_bounds__(256) void k_final(float4* __restrict__ acc,
                                               const float4* __restrict__ B) {
    const int stride = gridDim.x * blockDim.x;
    for (int i = blockIdx.x * blockDim.x + threadIdx.x; i < TOTAL4; i += stride) {
        float4 a = acc[i];
        const float4 b = B[i];
        a.x = (a.x + b.x) * 0.25f;
        a.y = (a.y + b.y) * 0.25f;
        a.z = (a.z + b.z) * 0.25f;
        a.w = (a.w + b.w) * 0.25f;
        acc[i] = a;
    }
}

extern "C" void kernel_launch(void* const* d_in, const int* in_sizes, int n_in,
                              void* d_out, int out_size, void* d_ws, size_t ws_size,
                              hipStream_t stream) {
    const float* user = (const float*)d_in[0];
    const float* item = (const float*)d_in[1];
    const float* val  = (const float*)d_in[2];
    const int*   row  = (const int*)d_in[3];
    const int*   col  = (const int*)d_in[4];

    float* acc = (float*)d_out;          // running sum, becomes mean at the end
    float* A   = (float*)d_ws;           // current layer embedding
    float* B   = A + TOTAL;              // next layer embedding

    const int eltBlocks = 2048;          // grid-stride elementwise kernels

    k_init<<<eltBlocks, 256, 0, stream>>>((const float4*)user, (const float4*)item,
                                          (float4*)A, (float4*)acc);

    for (int layer = 0; layer < 3; ++layer) {
        hipMemsetAsync(B, 0, (size_t)TOTAL * sizeof(float), stream);
        k_spmm<<<2048, 256, 0, stream>>>(A, B, val, row, col);
        if (layer < 2) {
            k_accadd<<<eltBlocks, 256, 0, stream>>>((float4*)acc, (const float4*)B);
            float* t = A; A = B; B = t;
        } else {
            k_final<<<eltBlocks, 256, 0, stream>>>((float4*)acc, (const float4*)B);
        }
    }
}

// Round 2
// 2383.539 us; speedup vs baseline: 2.6229x; 2.6229x over previous
//
#include <hip/hip_runtime.h>

#define N_USERS 100000
#define N_ITEMS 50000
#define N_NODES (N_USERS + N_ITEMS)   // 150000
#define DIM 64
#define NNZ_TOTAL 10000000
#define TOTAL (N_NODES * DIM)         // 9,600,000 floats
#define TOTAL4 (TOTAL / 4)            // 2,400,000 float4
#define USZ4 (N_USERS * DIM / 4)      // 1,600,000 float4

// ===========================================================================
// init: A = concat(user, item); acc(d_out) = same
// ===========================================================================
__global__ __launch_bounds__(256) void k_init(const float4* __restrict__ user,
                                              const float4* __restrict__ item,
                                              float4* __restrict__ A,
                                              float4* __restrict__ acc) {
    const int stride = gridDim.x * blockDim.x;
    for (int i = blockIdx.x * blockDim.x + threadIdx.x; i < TOTAL4; i += stride) {
        float4 v = (i < USZ4) ? user[i] : item[i - USZ4];
        A[i] = v;
        acc[i] = v;
    }
}

// ===========================================================================
// CSR build: histogram -> exclusive scan -> scatter
// ===========================================================================
__global__ __launch_bounds__(256) void k_hist(const int* __restrict__ row,
                                              int* __restrict__ counts) {
    const int stride = gridDim.x * blockDim.x;
    for (int e = blockIdx.x * blockDim.x + threadIdx.x; e < NNZ_TOTAL; e += stride) {
        atomicAdd(&counts[row[e]], 1);
    }
}

// single-block exclusive scan over N_NODES ints (1024 threads, Hillis-Steele)
__global__ __launch_bounds__(1024) void k_scan(const int* __restrict__ counts,
                                               int* __restrict__ offs) {
    __shared__ int lds[1024];
    __shared__ int carry;
    const int tid = threadIdx.x;
    if (tid == 0) carry = 0;
    __syncthreads();
    for (int base = 0; base < N_NODES; base += 1024) {
        const int i = base + tid;
        const int x = (i < N_NODES) ? counts[i] : 0;
        lds[tid] = x;
        __syncthreads();
        int v = x;
        for (int off = 1; off < 1024; off <<= 1) {
            const int y = (tid >= off) ? lds[tid - off] : 0;
            __syncthreads();
            v += y;
            lds[tid] = v;
            __syncthreads();
        }
        // v = inclusive scan of this chunk
        if (i < N_NODES) offs[i] = carry + (v - x);   // exclusive
        __syncthreads();                // all carry reads done
        if (tid == 0) carry += lds[1023];
        __syncthreads();
    }
    if (tid == 0) offs[N_NODES] = carry;
}

__global__ __launch_bounds__(256) void k_copy_offs(const int* __restrict__ offs,
                                                   int* __restrict__ cur) {
    const int i = blockIdx.x * blockDim.x + threadIdx.x;
    if (i < N_NODES) cur[i] = offs[i];
}

__global__ __launch_bounds__(256) void k_scatter(const int* __restrict__ row,
                                                 const int* __restrict__ col,
                                                 const float* __restrict__ val,
                                                 int* __restrict__ cur,
                                                 int* __restrict__ colv,
                                                 float* __restrict__ valv) {
    const int stride = gridDim.x * blockDim.x;
    for (int e = blockIdx.x * blockDim.x + threadIdx.x; e < NNZ_TOTAL; e += stride) {
        const int p = atomicAdd(&cur[row[e]], 1);
        colv[p] = col[e];
        valv[p] = val[e];
    }
}

// ===========================================================================
// CSR SpMM: one wave per row. lane = sub*16 + d4; sub = edge slot (4 edges in
// flight), d4 = float4 index within the 64-dim row. Register accumulation,
// cross-slot shfl_xor reduce, single store. acc update fused.
// ===========================================================================
template <bool FINAL>
__global__ __launch_bounds__(256) void k_spmm_csr(const float4* __restrict__ A4,
                                                  float4* __restrict__ B4,
                                                  float4* __restrict__ ACC4,
                                                  const int* __restrict__ offs,
                                                  const int* __restrict__ colv,
                                                  const float* __restrict__ valv) {
    const int lane = threadIdx.x & 63;
    const int sub  = lane >> 4;
    const int d4   = lane & 15;
    const int r = blockIdx.x * 4 + (threadIdx.x >> 6);
    if (r >= N_NODES) return;
    const int s = offs[r];
    const int e = offs[r + 1];
    float4 acc = make_float4(0.f, 0.f, 0.f, 0.f);
    for (int j = s + sub; j < e; j += 4) {
        const int c = colv[j];
        const float v = valv[j];
        const float4 g = A4[(size_t)c * 16 + d4];
        acc.x += v * g.x;
        acc.y += v * g.y;
        acc.z += v * g.z;
        acc.w += v * g.w;
    }
    // reduce across the 4 edge slots (lanes l, l^16, l^32, l^48)
    #pragma unroll
    for (int m = 16; m <= 32; m <<= 1) {
        acc.x += __shfl_xor(acc.x, m, 64);
        acc.y += __shfl_xor(acc.y, m, 64);
        acc.z += __shfl_xor(acc.z, m, 64);
        acc.w += __shfl_xor(acc.w, m, 64);
    }
    if (sub == 0) {
        const size_t idx = (size_t)r * 16 + d4;
        float4 a = ACC4[idx];
        if (FINAL) {
            a.x = (a.x + acc.x) * 0.25f;
            a.y = (a.y + acc.y) * 0.25f;
            a.z = (a.z + acc.z) * 0.25f;
            a.w = (a.w + acc.w) * 0.25f;
            ACC4[idx] = a;
        } else {
            B4[idx] = acc;
            a.x += acc.x;
            a.y += acc.y;
            a.z += acc.z;
            a.w += acc.w;
            ACC4[idx] = a;
        }
    }
}

// ===========================================================================
// Fallback (round-1 atomic path) if ws is too small for CSR
// ===========================================================================
__global__ __launch_bounds__(256) void k_spmm_atomic(const float* __restrict__ A,
                                                     float* __restrict__ B,
                                                     const float* __restrict__ val,
                                                     const int* __restrict__ row,
                                                     const int* __restrict__ col) {
    const int lane = threadIdx.x & 63;
    int wave = blockIdx.x * (blockDim.x >> 6) + (threadIdx.x >> 6);
    const int nw = gridDim.x * (blockDim.x >> 6);
    for (int e = wave; e < NNZ_TOTAL; e += nw) {
        const int r = row[e];
        const int c = col[e];
        const float v = val[e];
        const float x = A[c * DIM + lane];
        unsafeAtomicAdd(&B[r * DIM + lane], v * x);
    }
}

__global__ __launch_bounds__(256) void k_accadd(float4* __restrict__ acc,
                                                const float4* __restrict__ B) {
    const int stride = gridDim.x * blockDim.x;
    for (int i = blockIdx.x * blockDim.x + threadIdx.x; i < TOTAL4; i += stride) {
        float4 a = acc[i];
        const float4 b = B[i];
        a.x += b.x; a.y += b.y; a.z += b.z; a.w += b.w;
        acc[i] = a;
    }
}

__global__ __launch_bounds__(256) void k_final(float4* __restrict__ acc,
                                               const float4* __restrict__ B) {
    const int stride = gridDim.x * blockDim.x;
    for (int i = blockIdx.x * blockDim.x + threadIdx.x; i < TOTAL4; i += stride) {
        float4 a = acc[i];
        const float4 b = B[i];
        a.x = (a.x + b.x) * 0.25f;
        a.y = (a.y + b.y) * 0.25f;
        a.z = (a.z + b.z) * 0.25f;
        a.w = (a.w + b.w) * 0.25f;
        acc[i] = a;
    }
}

extern "C" void kernel_launch(void* const* d_in, const int* in_sizes, int n_in,
                              void* d_out, int out_size, void* d_ws, size_t ws_size,
                              hipStream_t stream) {
    const float* user = (const float*)d_in[0];
    const float* item = (const float*)d_in[1];
    const float* val  = (const float*)d_in[2];
    const int*   row  = (const int*)d_in[3];
    const int*   col  = (const int*)d_in[4];

    float* acc = (float*)d_out;

    // ws layout
    float* A    = (float*)d_ws;                 // TOTAL
    float* B    = A + TOTAL;                    // TOTAL
    int*   colv = (int*)(B + TOTAL);            // NNZ
    float* valv = (float*)(colv + NNZ_TOTAL);   // NNZ
    int* counts = (int*)(valv + NNZ_TOTAL);     // N_NODES
    int* offs   = counts + N_NODES;             // N_NODES + 1
    int* cur    = offs + N_NODES + 1;           // N_NODES

    const size_t needed = ((size_t)2 * TOTAL + 2 * NNZ_TOTAL + 3 * N_NODES + 1) * 4;
    const int eltBlocks = 2048;

    k_init<<<eltBlocks, 256, 0, stream>>>((const float4*)user, (const float4*)item,
                                          (float4*)A, (float4*)acc);

    if (ws_size >= needed) {
        // ---- build CSR ----
        hipMemsetAsync(counts, 0, (size_t)N_NODES * sizeof(int), stream);
        k_hist<<<2048, 256, 0, stream>>>(row, counts);
        k_scan<<<1, 1024, 0, stream>>>(counts, offs);
        k_copy_offs<<<(N_NODES + 255) / 256, 256, 0, stream>>>(offs, cur);
        k_scatter<<<2048, 256, 0, stream>>>(row, col, val, cur, colv, valv);

        // ---- 3 SpMM layers ----
        const int rowBlocks = N_NODES / 4;   // 4 waves (rows) per 256-thread block
        k_spmm_csr<false><<<rowBlocks, 256, 0, stream>>>(
            (const float4*)A, (float4*)B, (float4*)acc, offs, colv, valv);
        k_spmm_csr<false><<<rowBlocks, 256, 0, stream>>>(
            (const float4*)B, (float4*)A, (float4*)acc, offs, colv, valv);
        k_spmm_csr<true><<<rowBlocks, 256, 0, stream>>>(
            (const float4*)A, (float4*)B, (float4*)acc, offs, colv, valv);
    } else {
        // ---- fallback: atomic scatter path ----
        float* Af = A;
        float* Bf = B;
        for (int layer = 0; layer < 3; ++layer) {
            hipMemsetAsync(Bf, 0, (size_t)TOTAL * sizeof(float), stream);
            k_spmm_atomic<<<2048, 256, 0, stream>>>(Af, Bf, val, row, col);
            if (layer < 2) {
                k_accadd<<<eltBlocks, 256, 0, stream>>>((float4*)acc, (const float4*)Bf);
                float* t = Af; Af = Bf; Bf = t;
            } else {
                k_final<<<eltBlocks, 256, 0, stream>>>((float4*)acc, (const float4*)Bf);
            }
        }
    }
}